// Round 8
// baseline (430.590 us; speedup 1.0000x reference)
//
#include <hip/hip_runtime.h>
#include <cstdint>
#include <cstddef>

#define T_STEPS 1024
#define SEG     16
#define NSEG    (T_STEPS / SEG)   // 64 segments
#define NBLK    256               // 512 batch / 2 per block
#define LOG2E   1.4426950408889634f

typedef __attribute__((ext_vector_type(8))) _Float16 half8;
typedef __attribute__((ext_vector_type(4))) float    f32x4;
typedef __attribute__((ext_vector_type(4))) int      i32x4;

static __device__ __forceinline__ float fexp2(float x) {
#if defined(__has_builtin) && __has_builtin(__builtin_amdgcn_exp2f)
  return __builtin_amdgcn_exp2f(x);
#else
  return __exp2f(x);
#endif
}

static __device__ __forceinline__ half8 load8s(const float* s, float sc) {
  float4 a = ((const float4*)s)[0];
  float4 b = ((const float4*)s)[1];
  half8 h;
  h[0] = (_Float16)(a.x * sc); h[1] = (_Float16)(a.y * sc);
  h[2] = (_Float16)(a.z * sc); h[3] = (_Float16)(a.w * sc);
  h[4] = (_Float16)(b.x * sc); h[5] = (_Float16)(b.y * sc);
  h[6] = (_Float16)(b.z * sc); h[7] = (_Float16)(b.w * sc);
  return h;
}
// quantize 16 contiguous floats with scale s -> 16 i8 packed in 4 dwords
static __device__ __forceinline__ i32x4 quant16(const float* src, float s) {
  union { i32x4 v; signed char b[16]; } u;
  #pragma unroll
  for (int j = 0; j < 16; ++j) u.b[j] = (signed char)__float2int_rn(src[j] * s);
  return u.v;
}

// lgkm-only workgroup barrier (R8-verified): global loads float across it.
static __device__ __forceinline__ void barrier_lds() {
  __asm__ volatile("s_waitcnt lgkmcnt(0)\n\ts_barrier" ::: "memory");
}

// R24 = R23 resubmit (R7 bench was the same infra failure mode as R5, which
// cleared on resubmission in R6; kernel audit: LDS 132.6KB, uniform barriers,
// bounded bpermute addrs (<256B), no OOB, no data-dependent loops).
// Experiment: R22 (339us) + two serial-chain cuts. Calibrated model from
// R18/R19: wall(n chains/SIMD) = n*B + S, B~400 (SIMD-busy) S~385 (dep
// stall); R18: 785 ✓, R19: 1185 ✓(measured 1187). At n=1 wall = B+S =
// serial step time -> only lever is shortening the step. Two cuts:
// (1) h-exchange via pack+bpermute (~75-90cy vs ~150 LDS roundtrip):
//     P1 quad_perm(1,0,3,2) pair-pack, P2 quad_perm(2,3,0,1) quad-pack
//     (R19/R20 correctness-verified) -> every lane in quad j holds dword of
//     bytes 4j..4j+3; then 4 independent ds_bpermute with LOOP-INVARIANT
//     addresses (lane 16q+4m+(l&3)) fetch the A-frag dwords directly.
//     Replaces R20's 13-op serial row_ror/cndmask tail AND R18's
//     ds_write->lgkm->ds_read_b128. af loop-carried (R20 pattern); L1 keeps
//     the off-chain ring byte write (feeds xg2 producer); h2ring REMOVED.
// (2) transcendental fusion 10->8 per step (algebraically exact):
//     gi*gg = (1-Eg)*rcp((1+Ei)(1+Eg));  go*127*tanh(c) =
//     (127E-127)*rcp((1+Eo)(1+E)).  -2 rcp = -16cy issue + chain.
// Everything else identical to R22 (roles, SEG=16, 66 phases, ring/dbuf
// parity proofs, producers, epilogue, quant scheme).
__global__ __launch_bounds__(512, 2) void lstm_fused(
    const float* __restrict__ x,
    const float* __restrict__ w_ih1, const float* __restrict__ w_hh1,
    const float* __restrict__ b_ih1, const float* __restrict__ b_hh1,
    const float* __restrict__ w_ih2, const float* __restrict__ w_hh2,
    const float* __restrict__ b_ih2, const float* __restrict__ b_hh2,
    const float* __restrict__ fc1_w, const float* __restrict__ fc1_b,
    const float* __restrict__ fc2_w, const float* __restrict__ fc2_b,
    const float* __restrict__ ln_g, const float* __restrict__ ln_b,
    float* __restrict__ out)
{
  __shared__ __align__(16) signed char h1ring[32][2][64];   // 4 KB
  __shared__ __align__(16) float xg1b[2][SEG][2][64][4];    // 64 KB (dbuf)
  __shared__ __align__(16) float xg2b[2][SEG][2][64][4];    // 64 KB (dbuf)
  __shared__ __align__(16) float hfin[2][64];
  __shared__ __align__(16) float y1s[2][128];
  __shared__ __align__(16) float y2s[2][128];
  __shared__ float redmu[2], redrs[2];

  const int t   = threadIdx.x;
  const int blk = blockIdx.x;
  const int l   = t & 63;
  const int w   = t >> 6;       // wave role 0..7
  const int col = l & 15;
  const int q   = l >> 4;       // quad (K-slice)
  const int myb = w & 1;        // recurrence waves: batch; producers: k-half
  const int kbase = (w & 1) * 2;

  // ---- zero h1 ring (h_{-1}=0 for producer's first reads; rec uses af=0) ----
  ((int*)h1ring)[t]       = 0;
  ((int*)h1ring)[t + 512] = 0;

  const i32x4 zi = (i32x4){0, 0, 0, 0};
  f32x4 zf; zf[0] = 0.f; zf[1] = 0.f; zf[2] = 0.f; zf[3] = 0.f;

  // ---- stationary per-role weights ----
  i32x4 wq[4][4];      // rec waves: W_hh (full)
  i32x4 wq2[4][2];     // xg2 producers: W_ih2 half
  half8 wbx[4][2];     // xg1 producers: W_ih1 half (f16, log2e-folded)
  f32x4 fsa;           // rec: this lane's unit row scales (4 gates)
  float fsx[4][2];     // xg2 prod: dequant scales
  float bL[4][2];      // prods: log2e-scaled biases

  if (w < 4) {
    const float* W = (w < 2) ? w_hh1 : w_hh2;
    float fsq[4][4];
    #pragma unroll
    for (int g = 0; g < 4; ++g) {
      #pragma unroll
      for (int k = 0; k < 4; ++k) {
        const int r = g * 64 + k * 16 + col;       // unit u = k*16+col, gate g
        const float* p = W + r * 64 + q * 16;
        float m = 0.0f;
        #pragma unroll
        for (int j = 0; j < 16; ++j) m = fmaxf(m, fabsf(p[j]));
        m = fmaxf(m, __shfl_xor(m, 16, 64));
        m = fmaxf(m, __shfl_xor(m, 32, 64));
        wq[g][k] = quant16(p, 127.0f / m);
        fsq[g][k] = m * (LOG2E / 16129.0f);
      }
    }
    // lane's unit is u = l = q*16+col -> needs fsq[g][q] (static-index select)
    #pragma unroll
    for (int g = 0; g < 4; ++g) {
      const float v01 = (q & 1) ? fsq[g][1] : fsq[g][0];
      const float v23 = (q & 1) ? fsq[g][3] : fsq[g][2];
      fsa[g] = (q & 2) ? v23 : v01;
    }
  } else if (w < 6) {
    #pragma unroll
    for (int g = 0; g < 4; ++g) {
      #pragma unroll
      for (int k2 = 0; k2 < 2; ++k2) {
        const int r = g * 64 + (kbase + k2) * 16 + col;
        const float* p = w_ih2 + r * 64 + q * 16;
        float m = 0.0f;
        #pragma unroll
        for (int j = 0; j < 16; ++j) m = fmaxf(m, fabsf(p[j]));
        m = fmaxf(m, __shfl_xor(m, 16, 64));
        m = fmaxf(m, __shfl_xor(m, 32, 64));
        wq2[g][k2] = quant16(p, 127.0f / m);
        fsx[g][k2] = m * (LOG2E / 16129.0f);
        bL[g][k2]  = (b_ih2[r] + b_hh2[r]) * LOG2E;
      }
    }
  } else {
    #pragma unroll
    for (int g = 0; g < 4; ++g) {
      #pragma unroll
      for (int k2 = 0; k2 < 2; ++k2) {
        const int r = g * 64 + (kbase + k2) * 16 + col;
        wbx[g][k2] = load8s(w_ih1 + r * 32 + q * 8, LOG2E);
        bL[g][k2]  = (b_ih1[r] + b_hh1[r]) * LOG2E;
      }
    }
  }

  // producer A-row mapping: row = l&15 = 2*t_local + batch
  const int tl  = (l & 15) >> 1;
  const int axb = l & 1;

  // ---- recurrence state (loop-carried registers) ----
  float c  = 0.0f;
  i32x4 af = zi;                    // h_{t-1} i8 A-frag (replicated rows)
  const int sh1 = (l & 1) << 3;
  const int sh2 = (l & 2) << 3;
  // loop-invariant bpermute byte-addresses: dword m from lane 16q+4m+(l&3)
  const int bpa0 = ((q << 4) + 0 + (l & 3)) << 2;
  const int bpa1 = ((q << 4) + 4 + (l & 3)) << 2;
  const int bpa2 = ((q << 4) + 8 + (l & 3)) << 2;
  const int bpa3 = ((q << 4) + 12 + (l & 3)) << 2;

  // ---- xg1 producers: log2e*(W_ih1 @ x) + b1 (k-half, 2 passes of 8t) ----
  auto produce_xg1 = [&](int tau) {
    float* dst = &xg1b[tau & 1][0][0][0][0];
    #pragma unroll
    for (int h8 = 0; h8 < 2; ++h8) {
      const float* xs = x + ((size_t)(2 * blk + axb) * T_STEPS +
                             (tau * SEG + h8 * 8 + tl)) * 32 + q * 8;
      const float4 va = ((const float4*)xs)[0];
      const float4 vb = ((const float4*)xs)[1];
      half8 xf;
      xf[0] = (_Float16)va.x; xf[1] = (_Float16)va.y;
      xf[2] = (_Float16)va.z; xf[3] = (_Float16)va.w;
      xf[4] = (_Float16)vb.x; xf[5] = (_Float16)vb.y;
      xf[6] = (_Float16)vb.z; xf[7] = (_Float16)vb.w;
      f32x4 accf[4][2];
      #pragma unroll
      for (int g = 0; g < 4; ++g)
        #pragma unroll
        for (int k2 = 0; k2 < 2; ++k2)
          accf[g][k2] = __builtin_amdgcn_mfma_f32_16x16x32_f16(xf, wbx[g][k2], zf, 0, 0, 0);
      #pragma unroll
      for (int k2 = 0; k2 < 2; ++k2) {
        #pragma unroll
        for (int r = 0; r < 4; ++r) {
          const int row = h8 * 16 + q * 4 + r;   // row = 2*t_local + batch
          f32x4 v;
          v[0] = accf[0][k2][r] + bL[0][k2];
          v[1] = accf[1][k2][r] + bL[1][k2];
          v[2] = accf[2][k2][r] + bL[2][k2];
          v[3] = accf[3][k2][r] + bL[3][k2];
          *(f32x4*)(dst + (size_t)(row * 64 + (kbase + k2) * 16 + col) * 4) = v;
        }
      }
    }
  };

  // ---- xg2 producers: b2 + fs*(W_ih2 @ h1) from ring (k-half, 2 passes) ----
  auto produce_xg2 = [&](int sg) {
    float* dst = &xg2b[sg & 1][0][0][0][0];
    #pragma unroll
    for (int h8 = 0; h8 < 2; ++h8) {
      const i32x4 a = *(const i32x4*)((const signed char*)h1ring +
                      (size_t)((((sg * SEG + h8 * 8 + tl) & 31) * 128) + axb * 64 + q * 16));
      i32x4 acc[4][2];
      #pragma unroll
      for (int g = 0; g < 4; ++g)
        #pragma unroll
        for (int k2 = 0; k2 < 2; ++k2)
          acc[g][k2] = __builtin_amdgcn_mfma_i32_16x16x64_i8(a, wq2[g][k2], zi, 0, 0, 0);
      #pragma unroll
      for (int k2 = 0; k2 < 2; ++k2) {
        #pragma unroll
        for (int r = 0; r < 4; ++r) {
          const int row = h8 * 16 + q * 4 + r;
          f32x4 v;
          v[0] = bL[0][k2] + fsx[0][k2] * (float)acc[0][k2][r];
          v[1] = bL[1][k2] + fsx[1][k2] * (float)acc[1][k2][r];
          v[2] = bL[2][k2] + fsx[2][k2] * (float)acc[2][k2][r];
          v[3] = bL[3][k2] + fsx[3][k2] * (float)acc[3][k2][r];
          *(f32x4*)(dst + (size_t)(row * 64 + (kbase + k2) * 16 + col) * 4) = v;
        }
      }
    }
  };

  // ---- recurrence: 16 steps; af loop-carried, h-share via pack+bpermute ----
  auto run_seg = [&](const float* XG, int t0, bool ring, bool fin) {
    // rolling xq prefetch: 8 in flight; step j8<8 consumes xq[j8] then
    // reloads it with the step j8+8 value (8 steps of latency cover).
    f32x4 xq[8];
    #pragma unroll
    for (int j = 0; j < 8; ++j)
      xq[j] = *(const f32x4*)(XG + (size_t)((j * 2 + myb) * 64 + l) * 4);
    __builtin_amdgcn_s_setprio(1);
    #pragma unroll
    for (int j8 = 0; j8 < SEG; ++j8) {
      const int tt = t0 + j8;
      const f32x4 xv = xq[j8 & 7];
      if (j8 < 8)
        xq[j8 & 7] = *(const f32x4*)(XG + (size_t)(((j8 + 8) * 2 + myb) * 64 + l) * 4);
      i32x4 acc[4][4];
      #pragma unroll
      for (int g = 0; g < 4; ++g)
        #pragma unroll
        for (int k = 0; k < 4; ++k)
          acc[g][k] = __builtin_amdgcn_mfma_i32_16x16x64_i8(af, wq[g][k], zi, 0, 0, 0);
      // lane's unit u = l lives in tile k = q (static-index cndmask tree)
      float p[4];
      #pragma unroll
      for (int g = 0; g < 4; ++g) {
        const int a01 = (q & 1) ? acc[g][1][0] : acc[g][0][0];
        const int a23 = (q & 1) ? acc[g][3][0] : acc[g][2][0];
        const int ai  = (q & 2) ? a23 : a01;
        p[g] = xv[g] + fsa[g] * (float)ai;
      }
      // fused gates (exact algebra, 5 exp2 + 3 rcp):
      //   gi*gg = (1-Eg) / ((1+Ei)(1+Eg));   E* = exp2(-p~) = e^{-p}
      //   h*127 = (127E-127) / ((1+Eo)(1+E)),  E = e^{2c}
      const float Ei = fexp2(-p[0]);
      const float Ef = fexp2(-p[1]);
      const float Eg = fexp2(-(p[2] + p[2]));
      const float Eo = fexp2(-p[3]);
      const float gf = __builtin_amdgcn_rcpf(1.0f + Ef);
      const float ig = (1.0f - Eg) *
                       __builtin_amdgcn_rcpf((1.0f + Ei) * (1.0f + Eg));
      c = gf * c + ig;
      const float E  = fexp2(c * (2.0f * LOG2E));
      const float hq = fmaf(127.0f, E, -127.0f) *
                       __builtin_amdgcn_rcpf((1.0f + Eo) * (1.0f + E));
      const int  B  = __float2int_rn(hq) & 255;
      if (ring)   // off-chain byte write for the xg2 producer
        ((signed char*)h1ring)[(tt & 31) * 128 + myb * 64 + l] = (signed char)B;
      if (fin && j8 == SEG - 1) hfin[myb][l] = hq * (1.0f / 127.0f);
      // pack: P1 pair (quad_perm 1,0,3,2), P2 quad (quad_perm 2,3,0,1)
      const int a1 = B << sh1;
      const int t1 = __builtin_amdgcn_mov_dpp(a1, 0xB1, 0xF, 0xF, false);
      const int u2 = a1 | t1;
      const int a2 = u2 << sh2;
      const int t2 = __builtin_amdgcn_mov_dpp(a2, 0x4E, 0xF, 0xF, false);
      const int D  = a2 | t2;   // every lane in quad j: bytes of lanes 4j..4j+3
      // gather A-frag dwords: af[m] = D of lane 16q+4m (loop-invariant addrs)
      i32x4 nf;
      nf[0] = __builtin_amdgcn_ds_bpermute(bpa0, D);
      nf[1] = __builtin_amdgcn_ds_bpermute(bpa1, D);
      nf[2] = __builtin_amdgcn_ds_bpermute(bpa2, D);
      nf[3] = __builtin_amdgcn_ds_bpermute(bpa3, D);
      af = nf;
    }
    __builtin_amdgcn_s_setprio(0);
  };

  // ---- prime xg1 for segment 0 (ring zero-writes also drain here) ----
  if (w >= 6) produce_xg1(0);
  barrier_lds();

  // ---- segmented pipeline, 66 phases ----
  for (int s = 0; s <= NSEG + 1; ++s) {
    if (w < 2) {
      if (s < NSEG)
        run_seg(&xg1b[s & 1][0][0][0][0], s * SEG, true, false);
    } else if (w < 4) {
      const int sg = s - 2;
      if (sg >= 0)
        run_seg(&xg2b[sg & 1][0][0][0][0], sg * SEG, false, sg == NSEG - 1);
    } else if (w < 6) {
      const int sg = s - 1;
      if (sg >= 0 && sg < NSEG) produce_xg2(sg);
    } else {
      if (s + 1 < NSEG) produce_xg1(s + 1);
    }
    barrier_lds();
  }

  __syncthreads();   // full drain before epilogue

  // ---- head: y = LN(relu(hT@fc1^T+b1)@fc2^T+b2), 2 batch rows ----
  if (t < 256) {
    const int bi = t >> 7, j = t & 127;
    float accv = fc1_b[j];
    const float4* w4 = (const float4*)(fc1_w + j * 64);
    const float4* h4 = (const float4*)hfin[bi];
    #pragma unroll
    for (int qq = 0; qq < 16; ++qq) {
      float4 wv = w4[qq]; float4 hv = h4[qq];
      accv += wv.x * hv.x + wv.y * hv.y + wv.z * hv.z + wv.w * hv.w;
    }
    y1s[bi][j] = fmaxf(accv, 0.0f);
  }
  __syncthreads();
  if (t < 256) {
    const int bi = t >> 7, j = t & 127;
    float accv = fc2_b[j];
    const float4* w4 = (const float4*)(fc2_w + j * 128);
    const float4* y4 = (const float4*)y1s[bi];
    #pragma unroll
    for (int qq = 0; qq < 32; ++qq) {
      float4 wv = w4[qq]; float4 yv = y4[qq];
      accv += wv.x * yv.x + wv.y * yv.y + wv.z * yv.z + wv.w * yv.w;
    }
    y2s[bi][j] = accv;
  }
  __syncthreads();
  if (t < 128) {
    const int bi = t >> 6, jj = t & 63;
    float s  = y2s[bi][jj] + y2s[bi][64 + jj];
    float qs = y2s[bi][jj] * y2s[bi][jj] + y2s[bi][64 + jj] * y2s[bi][64 + jj];
    #pragma unroll
    for (int off = 32; off > 0; off >>= 1) {
      s  += __shfl_down(s, off, 64);
      qs += __shfl_down(qs, off, 64);
    }
    if (jj == 0) {
      const float mu  = s * (1.0f / 128.0f);
      const float var = qs * (1.0f / 128.0f) - mu * mu;
      redmu[bi] = mu;
      redrs[bi] = rsqrtf(var + 1e-5f);
    }
  }
  __syncthreads();
  if (t < 256) {
    const int bi = t >> 7, j = t & 127;
    out[(size_t)(2 * blk + bi) * 128 + j] =
        (y2s[bi][j] - redmu[bi]) * redrs[bi] * ln_g[j] + ln_b[j];
  }
}

extern "C" void kernel_launch(void* const* d_in, const int* in_sizes, int n_in,
                              void* d_out, int out_size, void* d_ws, size_t ws_size,
                              hipStream_t stream) {
  const float* x     = (const float*)d_in[0];
  const float* w_ih1 = (const float*)d_in[1];
  const float* w_hh1 = (const float*)d_in[2];
  const float* b_ih1 = (const float*)d_in[3];
  const float* b_hh1 = (const float*)d_in[4];
  const float* w_ih2 = (const float*)d_in[5];
  const float* w_hh2 = (const float*)d_in[6];
  const float* b_ih2 = (const float*)d_in[7];
  const float* b_hh2 = (const float*)d_in[8];
  const float* fc1_w = (const float*)d_in[9];
  const float* fc1_b = (const float*)d_in[10];
  const float* fc2_w = (const float*)d_in[11];
  const float* fc2_b = (const float*)d_in[12];
  const float* ln_g  = (const float*)d_in[13];
  const float* ln_b  = (const float*)d_in[14];
  float* out = (float*)d_out;

  lstm_fused<<<NBLK, 512, 0, stream>>>(x, w_ih1, w_hh1, b_ih1, b_hh1,
                                       w_ih2, w_hh2, b_ih2, b_hh2,
                                       fc1_w, fc1_b, fc2_w, fc2_b,
                                       ln_g, ln_b, out);
}

// Round 9
// 408.587 us; speedup vs baseline: 1.0539x; 1.0539x over previous
//
#include <hip/hip_runtime.h>
#include <cstdint>
#include <cstddef>

#define T_STEPS 1024
#define SEG     16
#define NSEG    (T_STEPS / SEG)   // 64 segments
#define NBLK    256               // 512 batch / 2 per block
#define LOG2E   1.4426950408889634f

typedef __attribute__((ext_vector_type(8))) _Float16 half8;
typedef __attribute__((ext_vector_type(4))) float    f32x4;
typedef __attribute__((ext_vector_type(4))) int      i32x4;

static __device__ __forceinline__ float fexp2(float x) {
#if defined(__has_builtin) && __has_builtin(__builtin_amdgcn_exp2f)
  return __builtin_amdgcn_exp2f(x);
#else
  return __exp2f(x);
#endif
}

static __device__ __forceinline__ half8 load8s(const float* s, float sc) {
  float4 a = ((const float4*)s)[0];
  float4 b = ((const float4*)s)[1];
  half8 h;
  h[0] = (_Float16)(a.x * sc); h[1] = (_Float16)(a.y * sc);
  h[2] = (_Float16)(a.z * sc); h[3] = (_Float16)(a.w * sc);
  h[4] = (_Float16)(b.x * sc); h[5] = (_Float16)(b.y * sc);
  h[6] = (_Float16)(b.z * sc); h[7] = (_Float16)(b.w * sc);
  return h;
}
// quantize 16 contiguous floats with scale s -> 16 i8 packed in 4 dwords
static __device__ __forceinline__ i32x4 quant16(const float* src, float s) {
  union { i32x4 v; signed char b[16]; } u;
  #pragma unroll
  for (int j = 0; j < 16; ++j) u.b[j] = (signed char)__float2int_rn(src[j] * s);
  return u.v;
}

// lgkm-only workgroup barrier (R8-verified): global loads float across it.
static __device__ __forceinline__ void barrier_lds() {
  __asm__ volatile("s_waitcnt lgkmcnt(0)\n\ts_barrier" ::: "memory");
}

// R25 = R22 (339us, best) + ONLY the transcendental fusion from R24.
// R24 post-mortem: bundled {bpermute exchange, fusion} = 365us -> bpermute
// costs ~+90cy vs the LDS roundtrip (exchange ranking now fully measured:
// LDS 785 < DPP 833 < bpermute 846 cy/step) while fusion is worth ~-30cy and
// was numerically verified exact (absmax unchanged). This round isolates it:
// structure, exchange (ds_write byte -> ds_read_b128 ring), SEG=16, rolling
// xq refill, roles, parity proofs — ALL identical to R22. Only the gate math
// changes (10 -> 8 transcendentals, exact algebra):
//   gi*gg  = (1-Eg) * rcp((1+Ei)(1+Eg))      E* = e^{-p}
//   h*127  = (127E-127) * rcp((1+Eo)(1+E))   E  = e^{2c}
// Roles: w0/w1 L1 rec b0/b1 [s]; w2/w3 L2 rec b0/b1 [s-2];
// w4/w5 xg2 halves [s-1]; w6/w7 xg1 halves [s+1]. lgkm-only barrier/phase.
// Quant scheme unchanged (per-row i8 weights, h i8 scale 127, log2e folded).
__global__ __launch_bounds__(512, 2) void lstm_fused(
    const float* __restrict__ x,
    const float* __restrict__ w_ih1, const float* __restrict__ w_hh1,
    const float* __restrict__ b_ih1, const float* __restrict__ b_hh1,
    const float* __restrict__ w_ih2, const float* __restrict__ w_hh2,
    const float* __restrict__ b_ih2, const float* __restrict__ b_hh2,
    const float* __restrict__ fc1_w, const float* __restrict__ fc1_b,
    const float* __restrict__ fc2_w, const float* __restrict__ fc2_b,
    const float* __restrict__ ln_g, const float* __restrict__ ln_b,
    float* __restrict__ out)
{
  __shared__ __align__(16) signed char h1ring[32][2][64];   // 4 KB
  __shared__ __align__(16) signed char h2ring[2][2][64];    // 256 B
  __shared__ __align__(16) float xg1b[2][SEG][2][64][4];    // 64 KB (dbuf)
  __shared__ __align__(16) float xg2b[2][SEG][2][64][4];    // 64 KB (dbuf)
  __shared__ __align__(16) float hfin[2][64];
  __shared__ __align__(16) float y1s[2][128];
  __shared__ __align__(16) float y2s[2][128];
  __shared__ float redmu[2], redrs[2];

  const int t   = threadIdx.x;
  const int blk = blockIdx.x;
  const int l   = t & 63;
  const int w   = t >> 6;       // wave role 0..7
  const int col = l & 15;
  const int q   = l >> 4;       // quad (K-slice)
  const int myb = w & 1;        // recurrence waves: batch; producers: k-half
  const int kbase = (w & 1) * 2;

  // ---- zero h rings (h_{-1} = 0) ----
  ((int*)h1ring)[t]       = 0;
  ((int*)h1ring)[t + 512] = 0;
  if (t < 64) ((int*)h2ring)[t] = 0;

  const i32x4 zi = (i32x4){0, 0, 0, 0};
  f32x4 zf; zf[0] = 0.f; zf[1] = 0.f; zf[2] = 0.f; zf[3] = 0.f;

  // ---- stationary per-role weights ----
  i32x4 wq[4][4];      // w0-3: recurrence W_hh (full)
  i32x4 wq2[4][2];     // w4/w5: W_ih2 half
  half8 wbx[4][2];     // w6/w7: W_ih1 half (f16, log2e-folded)
  f32x4 fsa;           // w0-3: this lane's unit row scales (4 gates)
  float fsx[4][2];     // w4/w5: dequant scales
  float bL[4][2];      // w4-7: log2e-scaled biases

  if (w < 4) {
    const float* W = (w < 2) ? w_hh1 : w_hh2;
    float fsq[4][4];
    #pragma unroll
    for (int g = 0; g < 4; ++g) {
      #pragma unroll
      for (int k = 0; k < 4; ++k) {
        const int r = g * 64 + k * 16 + col;       // unit u = k*16+col, gate g
        const float* p = W + r * 64 + q * 16;
        float m = 0.0f;
        #pragma unroll
        for (int j = 0; j < 16; ++j) m = fmaxf(m, fabsf(p[j]));
        m = fmaxf(m, __shfl_xor(m, 16, 64));
        m = fmaxf(m, __shfl_xor(m, 32, 64));
        wq[g][k] = quant16(p, 127.0f / m);
        fsq[g][k] = m * (LOG2E / 16129.0f);
      }
    }
    // lane's unit is u = l = q*16+col -> needs fsq[g][q] (static-index select)
    #pragma unroll
    for (int g = 0; g < 4; ++g) {
      const float v01 = (q & 1) ? fsq[g][1] : fsq[g][0];
      const float v23 = (q & 1) ? fsq[g][3] : fsq[g][2];
      fsa[g] = (q & 2) ? v23 : v01;
    }
  } else if (w < 6) {
    #pragma unroll
    for (int g = 0; g < 4; ++g) {
      #pragma unroll
      for (int k2 = 0; k2 < 2; ++k2) {
        const int r = g * 64 + (kbase + k2) * 16 + col;
        const float* p = w_ih2 + r * 64 + q * 16;
        float m = 0.0f;
        #pragma unroll
        for (int j = 0; j < 16; ++j) m = fmaxf(m, fabsf(p[j]));
        m = fmaxf(m, __shfl_xor(m, 16, 64));
        m = fmaxf(m, __shfl_xor(m, 32, 64));
        wq2[g][k2] = quant16(p, 127.0f / m);
        fsx[g][k2] = m * (LOG2E / 16129.0f);
        bL[g][k2]  = (b_ih2[r] + b_hh2[r]) * LOG2E;
      }
    }
  } else {
    #pragma unroll
    for (int g = 0; g < 4; ++g) {
      #pragma unroll
      for (int k2 = 0; k2 < 2; ++k2) {
        const int r = g * 64 + (kbase + k2) * 16 + col;
        wbx[g][k2] = load8s(w_ih1 + r * 32 + q * 8, LOG2E);
        bL[g][k2]  = (b_ih1[r] + b_hh1[r]) * LOG2E;
      }
    }
  }

  // producer A-row mapping: row = l&15 = 2*t_local + batch
  const int tl  = (l & 15) >> 1;
  const int axb = l & 1;

  float c = 0.0f;

  // ---- w6/w7: xg1[tau] = log2e*(W_ih1 @ x) + b1 (k-half, 2 passes of 8t) ----
  auto produce_xg1 = [&](int tau) {
    float* dst = &xg1b[tau & 1][0][0][0][0];
    #pragma unroll
    for (int h8 = 0; h8 < 2; ++h8) {
      const float* xs = x + ((size_t)(2 * blk + axb) * T_STEPS +
                             (tau * SEG + h8 * 8 + tl)) * 32 + q * 8;
      const float4 va = ((const float4*)xs)[0];
      const float4 vb = ((const float4*)xs)[1];
      half8 xf;
      xf[0] = (_Float16)va.x; xf[1] = (_Float16)va.y;
      xf[2] = (_Float16)va.z; xf[3] = (_Float16)va.w;
      xf[4] = (_Float16)vb.x; xf[5] = (_Float16)vb.y;
      xf[6] = (_Float16)vb.z; xf[7] = (_Float16)vb.w;
      f32x4 accf[4][2];
      #pragma unroll
      for (int g = 0; g < 4; ++g)
        #pragma unroll
        for (int k2 = 0; k2 < 2; ++k2)
          accf[g][k2] = __builtin_amdgcn_mfma_f32_16x16x32_f16(xf, wbx[g][k2], zf, 0, 0, 0);
      #pragma unroll
      for (int k2 = 0; k2 < 2; ++k2) {
        #pragma unroll
        for (int r = 0; r < 4; ++r) {
          const int row = h8 * 16 + q * 4 + r;   // row = 2*t_local + batch
          f32x4 v;
          v[0] = accf[0][k2][r] + bL[0][k2];
          v[1] = accf[1][k2][r] + bL[1][k2];
          v[2] = accf[2][k2][r] + bL[2][k2];
          v[3] = accf[3][k2][r] + bL[3][k2];
          *(f32x4*)(dst + (size_t)(row * 64 + (kbase + k2) * 16 + col) * 4) = v;
        }
      }
    }
  };

  // ---- w4/w5: xg2[sg] = b2 + fs*(W_ih2 @ h1) from ring (k-half, 2 passes) ----
  auto produce_xg2 = [&](int sg) {
    float* dst = &xg2b[sg & 1][0][0][0][0];
    #pragma unroll
    for (int h8 = 0; h8 < 2; ++h8) {
      const i32x4 a = *(const i32x4*)((const signed char*)h1ring +
                      (size_t)((((sg * SEG + h8 * 8 + tl) & 31) * 128) + axb * 64 + q * 16));
      i32x4 acc[4][2];
      #pragma unroll
      for (int g = 0; g < 4; ++g)
        #pragma unroll
        for (int k2 = 0; k2 < 2; ++k2)
          acc[g][k2] = __builtin_amdgcn_mfma_i32_16x16x64_i8(a, wq2[g][k2], zi, 0, 0, 0);
      #pragma unroll
      for (int k2 = 0; k2 < 2; ++k2) {
        #pragma unroll
        for (int r = 0; r < 4; ++r) {
          const int row = h8 * 16 + q * 4 + r;
          f32x4 v;
          v[0] = bL[0][k2] + fsx[0][k2] * (float)acc[0][k2][r];
          v[1] = bL[1][k2] + fsx[1][k2] * (float)acc[1][k2][r];
          v[2] = bL[2][k2] + fsx[2][k2] * (float)acc[2][k2][r];
          v[3] = bL[3][k2] + fsx[3][k2] * (float)acc[3][k2][r];
          *(f32x4*)(dst + (size_t)(row * 64 + (kbase + k2) * 16 + col) * 4) = v;
        }
      }
    }
  };

  // ---- recurrence: 16 steps, one batch, one unit per lane, barrier-free ----
  auto run_seg = [&](const float* XG, signed char* RING, int RM, int t0, bool fin) {
    // rolling xq prefetch: 8 in flight; step j8<8 consumes xq[j8] then
    // reloads it with the step j8+8 value (8 steps of latency cover).
    f32x4 xq[8];
    #pragma unroll
    for (int j = 0; j < 8; ++j)
      xq[j] = *(const f32x4*)(XG + (size_t)((j * 2 + myb) * 64 + l) * 4);
    __builtin_amdgcn_s_setprio(1);
    #pragma unroll
    for (int j8 = 0; j8 < SEG; ++j8) {
      const int tt = t0 + j8;
      // previous h, replicated M: all lanes in a q-group read the same 16B
      const i32x4 a = *(const i32x4*)(RING + ((tt - 1) & RM) * 128 + myb * 64 + q * 16);
      const f32x4 xv = xq[j8 & 7];
      if (j8 < 8)
        xq[j8 & 7] = *(const f32x4*)(XG + (size_t)(((j8 + 8) * 2 + myb) * 64 + l) * 4);
      i32x4 acc[4][4];
      #pragma unroll
      for (int g = 0; g < 4; ++g)
        #pragma unroll
        for (int k = 0; k < 4; ++k)
          acc[g][k] = __builtin_amdgcn_mfma_i32_16x16x64_i8(a, wq[g][k], zi, 0, 0, 0);
      // lane's unit u = l lives in tile k = q (static-index cndmask tree)
      float p[4];
      #pragma unroll
      for (int g = 0; g < 4; ++g) {
        const int a01 = (q & 1) ? acc[g][1][0] : acc[g][0][0];
        const int a23 = (q & 1) ? acc[g][3][0] : acc[g][2][0];
        const int ai  = (q & 2) ? a23 : a01;
        p[g] = xv[g] + fsa[g] * (float)ai;
      }
      // fused gates (exact algebra, 5 exp2 + 3 rcp; R24-verified numerics):
      //   gi*gg = (1-Eg) / ((1+Ei)(1+Eg));   E* = e^{-p}
      //   h*127 = (127E-127) / ((1+Eo)(1+E)),  E = e^{2c}
      const float Ei = fexp2(-p[0]);
      const float Ef = fexp2(-p[1]);
      const float Eg = fexp2(-(p[2] + p[2]));
      const float Eo = fexp2(-p[3]);
      const float gf = __builtin_amdgcn_rcpf(1.0f + Ef);
      const float ig = (1.0f - Eg) *
                       __builtin_amdgcn_rcpf((1.0f + Ei) * (1.0f + Eg));
      c = gf * c + ig;
      const float E  = fexp2(c * (2.0f * LOG2E));
      const float hq = fmaf(127.0f, E, -127.0f) *
                       __builtin_amdgcn_rcpf((1.0f + Eo) * (1.0f + E));
      RING[(tt & RM) * 128 + myb * 64 + l] = (signed char)__float2int_rn(hq);
      if (fin && j8 == SEG - 1) hfin[myb][l] = hq * (1.0f / 127.0f);
    }
    __builtin_amdgcn_s_setprio(0);
  };

  // ---- prime xg1 for segment 0 (ring zero-writes also drain here) ----
  if (w >= 6) produce_xg1(0);
  barrier_lds();

  // ---- segmented pipeline, 66 phases ----
  for (int s = 0; s <= NSEG + 1; ++s) {
    if (w < 2) {
      if (s < NSEG)
        run_seg(&xg1b[s & 1][0][0][0][0], (signed char*)h1ring, 31, s * SEG, false);
    } else if (w < 4) {
      const int sg = s - 2;
      if (sg >= 0)
        run_seg(&xg2b[sg & 1][0][0][0][0], (signed char*)h2ring, 1, sg * SEG,
                sg == NSEG - 1);
    } else if (w < 6) {
      const int sg = s - 1;
      if (sg >= 0 && sg < NSEG) produce_xg2(sg);
    } else {
      if (s + 1 < NSEG) produce_xg1(s + 1);
    }
    barrier_lds();
  }

  __syncthreads();   // full drain before epilogue

  // ---- head: y = LN(relu(hT@fc1^T+b1)@fc2^T+b2), 2 batch rows ----
  if (t < 256) {
    const int bi = t >> 7, j = t & 127;
    float accv = fc1_b[j];
    const float4* w4 = (const float4*)(fc1_w + j * 64);
    const float4* h4 = (const float4*)hfin[bi];
    #pragma unroll
    for (int qq = 0; qq < 16; ++qq) {
      float4 wv = w4[qq]; float4 hv = h4[qq];
      accv += wv.x * hv.x + wv.y * hv.y + wv.z * hv.z + wv.w * hv.w;
    }
    y1s[bi][j] = fmaxf(accv, 0.0f);
  }
  __syncthreads();
  if (t < 256) {
    const int bi = t >> 7, j = t & 127;
    float accv = fc2_b[j];
    const float4* w4 = (const float4*)(fc2_w + j * 128);
    const float4* y4 = (const float4*)y1s[bi];
    #pragma unroll
    for (int qq = 0; qq < 32; ++qq) {
      float4 wv = w4[qq]; float4 yv = y4[qq];
      accv += wv.x * yv.x + wv.y * yv.y + wv.z * yv.z + wv.w * yv.w;
    }
    y2s[bi][j] = accv;
  }
  __syncthreads();
  if (t < 128) {
    const int bi = t >> 6, jj = t & 63;
    float s  = y2s[bi][jj] + y2s[bi][64 + jj];
    float qs = y2s[bi][jj] * y2s[bi][jj] + y2s[bi][64 + jj] * y2s[bi][64 + jj];
    #pragma unroll
    for (int off = 32; off > 0; off >>= 1) {
      s  += __shfl_down(s, off, 64);
      qs += __shfl_down(qs, off, 64);
    }
    if (jj == 0) {
      const float mu  = s * (1.0f / 128.0f);
      const float var = qs * (1.0f / 128.0f) - mu * mu;
      redmu[bi] = mu;
      redrs[bi] = rsqrtf(var + 1e-5f);
    }
  }
  __syncthreads();
  if (t < 256) {
    const int bi = t >> 7, j = t & 127;
    out[(size_t)(2 * blk + bi) * 128 + j] =
        (y2s[bi][j] - redmu[bi]) * redrs[bi] * ln_g[j] + ln_b[j];
  }
}

extern "C" void kernel_launch(void* const* d_in, const int* in_sizes, int n_in,
                              void* d_out, int out_size, void* d_ws, size_t ws_size,
                              hipStream_t stream) {
  const float* x     = (const float*)d_in[0];
  const float* w_ih1 = (const float*)d_in[1];
  const float* w_hh1 = (const float*)d_in[2];
  const float* b_ih1 = (const float*)d_in[3];
  const float* b_hh1 = (const float*)d_in[4];
  const float* w_ih2 = (const float*)d_in[5];
  const float* w_hh2 = (const float*)d_in[6];
  const float* b_ih2 = (const float*)d_in[7];
  const float* b_hh2 = (const float*)d_in[8];
  const float* fc1_w = (const float*)d_in[9];
  const float* fc1_b = (const float*)d_in[10];
  const float* fc2_w = (const float*)d_in[11];
  const float* fc2_b = (const float*)d_in[12];
  const float* ln_g  = (const float*)d_in[13];
  const float* ln_b  = (const float*)d_in[14];
  float* out = (float*)d_out;

  lstm_fused<<<NBLK, 512, 0, stream>>>(x, w_ih1, w_hh1, b_ih1, b_hh1,
                                       w_ih2, w_hh2, b_ih2, b_hh2,
                                       fc1_w, fc1_b, fc2_w, fc2_b,
                                       ln_g, ln_b, out);
}